// Round 9
// baseline (1076.471 us; speedup 1.0000x reference)
//
#include <hip/hip_runtime.h>
#include <hip/hip_bf16.h>

#define N_TOK 8192
#define DDIM  2048
#define HDIM  1408
#define ROWS_R 16384
#define ROWS_T 24576
#define MAXTILES 200
#define BM 128
#define BK 64

typedef unsigned short u16;
typedef unsigned int   u32;
typedef __bf16 bf16x8 __attribute__((ext_vector_type(8)));
typedef float  f32x4  __attribute__((ext_vector_type(4)));

__device__ __forceinline__ u16 f2bf(float f) {
  union { float f; u32 u; } v; v.f = f;
  u32 u = v.u;
  return (u16)((u + 0x7fffu + ((u >> 16) & 1u)) >> 16);
}
__device__ __forceinline__ float bf2f(u16 b) {
  union { u32 u; float f; } v; v.u = ((u32)b) << 16; return v.f;
}
// packed f32->bf16 (RNE), no builtin on gfx950 -> inline asm (T12)
__device__ __forceinline__ u32 pkbf(float lo, float hi) {
  u32 r;
  asm volatile("v_cvt_pk_bf16_f32 %0, %1, %2" : "=v"(r) : "v"(lo), "v"(hi));
  return r;
}

typedef __attribute__((address_space(1))) void gvoid;
typedef __attribute__((address_space(3))) void lvoid;
__device__ __forceinline__ void gload16(const void* g, void* l) {
  __builtin_amdgcn_global_load_lds((gvoid*)g, (lvoid*)l, 16, 0, 0);
}

// ---------------- gating (+ fused x -> bf16 conversion) ----------------
__global__ void k_gate(const float* __restrict__ x, const float* __restrict__ gw,
                       const float* __restrict__ bias, int* __restrict__ tok_idx,
                       float* __restrict__ wts, int* __restrict__ counts,
                       u16* __restrict__ xb) {
  int lane = threadIdx.x & 63;
  int n = blockIdx.x * 4 + (threadIdx.x >> 6);
  const float* xr = x + (size_t)n * DDIM;
  u16* xbr = xb + (size_t)n * DDIM;
  float acc[8];
#pragma unroll
  for (int e = 0; e < 8; ++e) acc[e] = 0.f;
#pragma unroll 2
  for (int j0 = 0; j0 < DDIM; j0 += 256) {
    float4 xv = *(const float4*)(xr + j0 + lane * 4);
    *(uint2*)(xbr + j0 + lane * 4) = make_uint2(pkbf(xv.x, xv.y), pkbf(xv.z, xv.w));
#pragma unroll
    for (int e = 0; e < 8; ++e) {
      float4 gv = *(const float4*)(gw + e * DDIM + j0 + lane * 4);
      acc[e] += xv.x * gv.x + xv.y * gv.y + xv.z * gv.z + xv.w * gv.w;
    }
  }
#pragma unroll
  for (int e = 0; e < 8; ++e) {
#pragma unroll
    for (int off = 32; off > 0; off >>= 1) acc[e] += __shfl_xor(acc[e], off);
  }
  if (lane == 0) {
    float m = acc[0];
    for (int e = 1; e < 8; ++e) m = fmaxf(m, acc[e]);
    float p[8];
    for (int e = 0; e < 8; ++e) p[e] = expf(acc[e] - m);
    float b0[8];
    for (int e = 0; e < 8; ++e) b0[e] = acc[e] + bias[e];
    int i0 = 0;
    for (int e = 1; e < 8; ++e) if (b0[e] > b0[i0]) i0 = e;
    int i1 = (i0 == 0) ? 1 : 0;
    for (int e = 0; e < 8; ++e) if (e != i0 && b0[e] > b0[i1]) i1 = e;
    float w0 = p[i0], w1 = p[i1], inv = 1.f / (w0 + w1);
    tok_idx[2 * n] = i0; tok_idx[2 * n + 1] = i1;
    wts[2 * n] = w0 * inv; wts[2 * n + 1] = w1 * inv;
    atomicAdd(&counts[i0], 1); atomicAdd(&counts[i1], 1);
  }
}

// ---------------- scan + tile table (BM=128 tiles) ----------------
__global__ void k_scan(const int* __restrict__ counts, int* __restrict__ offsets,
                       int* __restrict__ cursors, int* __restrict__ ntiles,
                       int4* __restrict__ tiles) {
  if (threadIdx.x != 0 || blockIdx.x != 0) return;
  int off = 0, idx = 0;
  for (int e = 0; e < 8; ++e) {
    offsets[e] = off; cursors[e] = 0;
    int T = counts[e];
    for (int r = 0; r < T; r += BM) {
      int nr = T - r; if (nr > BM) nr = BM;
      tiles[idx++] = make_int4(e, off + r, nr, 0);
    }
    off += T;
  }
  offsets[8] = off;
  for (int r = 0; r < N_TOK; r += BM)
    tiles[idx++] = make_int4(8, ROWS_R + r, BM, 0);
  *ntiles = idx;
}

// ---------------- build token lists ----------------
__global__ void k_build(const int* __restrict__ tok_idx, const int* __restrict__ offsets,
                        int* __restrict__ cursors, int* __restrict__ token_ids,
                        int* __restrict__ pos) {
  int n = blockIdx.x * blockDim.x + threadIdx.x;
  if (n >= N_TOK) return;
#pragma unroll
  for (int s = 0; s < 2; ++s) {
    int e = tok_idx[2 * n + s];
    int p = offsets[e] + atomicAdd(&cursors[e], 1);
    token_ids[p] = n;
    pos[2 * n + s] = p;
  }
  token_ids[ROWS_R + n] = n;
}

// ---------------- GEMM1: h = silu(x Wg^T) * (x Wu^T), f32 weights inline-converted ----------------
__global__ __launch_bounds__(256, 2) void k_gemm1(
    const u16* __restrict__ xb,
    const float* __restrict__ Wg, const float* __restrict__ Wsg,
    const float* __restrict__ Wu, const float* __restrict__ Wsu,
    const int* __restrict__ token_ids, const int* __restrict__ ntiles,
    const int4* __restrict__ tiles, u16* __restrict__ h) {
  __shared__ u16 As[128 * 64], Bgs[128 * 64], Bus[128 * 64];   // 48 KB

  int ntl = *ntiles;
  const int NBX = HDIM / 128;  // 11
  int nwg = NBX * ntl;
  int bid = blockIdx.x;
  if (bid >= nwg) return;
  // bijective XCD chunking; tile-major within chunk so neighbors share the A-tile
  int q8 = nwg >> 3, r8 = nwg & 7;
  int xcd = bid & 7, pp = bid >> 3;
  int lid = (xcd < r8 ? xcd * (q8 + 1) : r8 * (q8 + 1) + (xcd - r8) * q8) + pp;
  int tile = lid / NBX, bx = lid - tile * NBX;

  int4 tl = tiles[tile];
  int set = tl.x, grow = tl.y, nrows = tl.z;
  const float* wgb = (set < 8) ? Wg + (size_t)set * HDIM * DDIM : Wsg;
  const float* wub = (set < 8) ? Wu + (size_t)set * HDIM * DDIM : Wsu;

  int t = threadIdx.x;
  int wid = t >> 6, lane = t & 63;
  int wr = wid >> 1, wc = wid & 1;
  int l15 = lane & 15, lhi = lane >> 4;

  const u16* aptr[4]; const float* gptr[4]; const float* uptr[4];
#pragma unroll
  for (int i = 0; i < 4; ++i) {
    int chunk = i * 256 + t;
    int r = chunk >> 3, cc = chunk & 7;
    int c = cc ^ (r & 7);              // inverse-swizzled source column
    int rr = r < nrows ? r : nrows - 1;
    int tok = token_ids[grow + rr];
    aptr[i] = xb + (size_t)tok * DDIM + c * 8;
    size_t wroff = (size_t)(bx * 128 + r) * DDIM + c * 8;
    gptr[i] = wgb + wroff;
    uptr[i] = wub + wroff;
  }

  f32x4 accg[4][4], accu[4][4];
  f32x4 z = {0.f, 0.f, 0.f, 0.f};
#pragma unroll
  for (int m = 0; m < 4; ++m)
#pragma unroll
    for (int n = 0; n < 4; ++n) { accg[m][n] = z; accu[m][n] = z; }

  for (int k0 = 0; k0 < DDIM; k0 += BK) {
    __syncthreads();   // previous compute done; safe to overwrite LDS
#pragma unroll
    for (int i = 0; i < 4; ++i)
      gload16(aptr[i] + k0, (char*)As + (size_t)(i * 256 + t) * 16);
#pragma unroll
    for (int i = 0; i < 4; ++i) {
      float4 g0 = *(const float4*)(gptr[i] + k0);
      float4 g1 = *(const float4*)(gptr[i] + k0 + 4);
      float4 u0 = *(const float4*)(uptr[i] + k0);
      float4 u1 = *(const float4*)(uptr[i] + k0 + 4);
      *(uint4*)((char*)Bgs + (size_t)(i * 256 + t) * 16) =
          make_uint4(pkbf(g0.x, g0.y), pkbf(g0.z, g0.w), pkbf(g1.x, g1.y), pkbf(g1.z, g1.w));
      *(uint4*)((char*)Bus + (size_t)(i * 256 + t) * 16) =
          make_uint4(pkbf(u0.x, u0.y), pkbf(u0.z, u0.w), pkbf(u1.x, u1.y), pkbf(u1.z, u1.w));
    }
    __syncthreads();
#pragma unroll
    for (int kk = 0; kk < 2; ++kk) {
      int cch = kk * 4 + lhi;
      bf16x8 af[4], bg[4], bu[4];
#pragma unroll
      for (int m = 0; m < 4; ++m) {
        int r = wr * 64 + m * 16 + l15;
        af[m] = *(const bf16x8*)((const char*)As + r * 128 + ((cch ^ (r & 7)) * 16));
      }
#pragma unroll
      for (int n = 0; n < 4; ++n) {
        int r = wc * 64 + n * 16 + l15;
        int boff = r * 128 + ((cch ^ (r & 7)) * 16);
        bg[n] = *(const bf16x8*)((const char*)Bgs + boff);
        bu[n] = *(const bf16x8*)((const char*)Bus + boff);
      }
#pragma unroll
      for (int m = 0; m < 4; ++m)
#pragma unroll
        for (int n = 0; n < 4; ++n) {
          accg[m][n] = __builtin_amdgcn_mfma_f32_16x16x32_bf16(af[m], bg[n], accg[m][n], 0, 0, 0);
          accu[m][n] = __builtin_amdgcn_mfma_f32_16x16x32_bf16(af[m], bu[n], accu[m][n], 0, 0, 0);
        }
    }
  }

#pragma unroll
  for (int m = 0; m < 4; ++m) {
#pragma unroll
    for (int n = 0; n < 4; ++n) {
      int col = bx * 128 + wc * 64 + n * 16 + l15;
#pragma unroll
      for (int qq = 0; qq < 4; ++qq) {
        int rl = wr * 64 + m * 16 + lhi * 4 + qq;
        if (rl < nrows) {
          float g = accg[m][n][qq], u = accu[m][n][qq];
          float hv = g / (1.f + expf(-g)) * u;
          h[(size_t)(grow + rl) * HDIM + col] = f2bf(hv);
        }
      }
    }
  }
}

// ---------------- GEMM2: y = h Wd^T, f32 weights inline-converted ----------------
__global__ __launch_bounds__(256, 2) void k_gemm2(
    const u16* __restrict__ h,
    const float* __restrict__ Wd, const float* __restrict__ Wsd,
    const int* __restrict__ ntiles, const int4* __restrict__ tiles,
    u16* __restrict__ y) {
  __shared__ u16 As[128 * 64], Bs[128 * 64];   // 32 KB

  int ntl = *ntiles;
  const int NBX = DDIM / 128;  // 16
  int nwg = NBX * ntl;
  int bid = blockIdx.x;
  if (bid >= nwg) return;
  int q8 = nwg >> 3, r8 = nwg & 7;
  int xcd = bid & 7, pp = bid >> 3;
  int lid = (xcd < r8 ? xcd * (q8 + 1) : r8 * (q8 + 1) + (xcd - r8) * q8) + pp;
  int tile = lid / NBX, bx = lid - tile * NBX;

  int4 tl = tiles[tile];
  int set = tl.x, grow = tl.y, nrows = tl.z;
  const float* wdb = (set < 8) ? Wd + (size_t)set * DDIM * HDIM : Wsd;

  int t = threadIdx.x;
  int wid = t >> 6, lane = t & 63;
  int wr = wid >> 1, wc = wid & 1;
  int l15 = lane & 15, lhi = lane >> 4;

  const u16* aptr[4]; const float* bptr[4];
#pragma unroll
  for (int i = 0; i < 4; ++i) {
    int chunk = i * 256 + t;
    int r = chunk >> 3, cc = chunk & 7;
    int c = cc ^ (r & 7);
    aptr[i] = h + (size_t)(grow + r) * HDIM + c * 8;
    bptr[i] = wdb + (size_t)(bx * 128 + r) * HDIM + c * 8;
  }

  f32x4 acc[4][4];
  f32x4 z = {0.f, 0.f, 0.f, 0.f};
#pragma unroll
  for (int m = 0; m < 4; ++m)
#pragma unroll
    for (int n = 0; n < 4; ++n) acc[m][n] = z;

  for (int k0 = 0; k0 < HDIM; k0 += BK) {
    __syncthreads();
#pragma unroll
    for (int i = 0; i < 4; ++i)
      gload16(aptr[i] + k0, (char*)As + (size_t)(i * 256 + t) * 16);
#pragma unroll
    for (int i = 0; i < 4; ++i) {
      float4 b0 = *(const float4*)(bptr[i] + k0);
      float4 b1 = *(const float4*)(bptr[i] + k0 + 4);
      *(uint4*)((char*)Bs + (size_t)(i * 256 + t) * 16) =
          make_uint4(pkbf(b0.x, b0.y), pkbf(b0.z, b0.w), pkbf(b1.x, b1.y), pkbf(b1.z, b1.w));
    }
    __syncthreads();
#pragma unroll
    for (int kk = 0; kk < 2; ++kk) {
      int cch = kk * 4 + lhi;
      bf16x8 af[4], bf[4];
#pragma unroll
      for (int m = 0; m < 4; ++m) {
        int r = wr * 64 + m * 16 + l15;
        af[m] = *(const bf16x8*)((const char*)As + r * 128 + ((cch ^ (r & 7)) * 16));
      }
#pragma unroll
      for (int n = 0; n < 4; ++n) {
        int r = wc * 64 + n * 16 + l15;
        bf[n] = *(const bf16x8*)((const char*)Bs + r * 128 + ((cch ^ (r & 7)) * 16));
      }
#pragma unroll
      for (int m = 0; m < 4; ++m)
#pragma unroll
        for (int n = 0; n < 4; ++n)
          acc[m][n] = __builtin_amdgcn_mfma_f32_16x16x32_bf16(af[m], bf[n], acc[m][n], 0, 0, 0);
    }
  }

#pragma unroll
  for (int m = 0; m < 4; ++m) {
#pragma unroll
    for (int n = 0; n < 4; ++n) {
      int col = bx * 128 + wc * 64 + n * 16 + l15;
#pragma unroll
      for (int qq = 0; qq < 4; ++qq) {
        int rl = wr * 64 + m * 16 + lhi * 4 + qq;
        if (rl < nrows)
          y[(size_t)(grow + rl) * DDIM + col] = f2bf(acc[m][n][qq]);
      }
    }
  }
}

// ---------------- combine ----------------
__global__ void k_comb(const u16* __restrict__ y, const int* __restrict__ pos,
                       const float* __restrict__ wts, float* __restrict__ out) {
  int n = blockIdx.x;
  int c8 = threadIdx.x;
  int p0 = pos[2 * n], p1 = pos[2 * n + 1];
  float w0 = wts[2 * n], w1 = wts[2 * n + 1];
  uint4 a = ((const uint4*)(y + (size_t)p0 * DDIM))[c8];
  uint4 b = ((const uint4*)(y + (size_t)p1 * DDIM))[c8];
  uint4 c = ((const uint4*)(y + (size_t)(ROWS_R + n) * DDIM))[c8];
  float* o = out + (size_t)n * DDIM + c8 * 8;
#pragma unroll
  for (int j = 0; j < 4; ++j) {
    u32 ua = ((const u32*)&a)[j], ub = ((const u32*)&b)[j], uc = ((const u32*)&c)[j];
    o[2 * j]     = w0 * bf2f((u16)(ua & 0xffff)) + w1 * bf2f((u16)(ub & 0xffff)) + bf2f((u16)(uc & 0xffff));
    o[2 * j + 1] = w0 * bf2f((u16)(ua >> 16))    + w1 * bf2f((u16)(ub >> 16))    + bf2f((u16)(uc >> 16));
  }
}

extern "C" void kernel_launch(void* const* d_in, const int* in_sizes, int n_in,
                              void* d_out, int out_size, void* d_ws, size_t ws_size,
                              hipStream_t stream) {
  const float* x    = (const float*)d_in[0];
  const float* gw   = (const float*)d_in[1];
  const float* bias = (const float*)d_in[2];
  const float* Wg   = (const float*)d_in[3];
  const float* Wu   = (const float*)d_in[4];
  const float* Wd   = (const float*)d_in[5];
  const float* Wsg  = (const float*)d_in[6];
  const float* Wsu  = (const float*)d_in[7];
  const float* Wsd  = (const float*)d_in[8];
  float* out = (float*)d_out;

  char* ws = (char*)d_ws;
  size_t off = 0;
  auto alloc = [&](size_t bytes) -> void* {
    void* p = ws + off;
    off += (bytes + 255) & ~(size_t)255;
    return p;
  };
  u16* xb  = (u16*)alloc((size_t)N_TOK * DDIM * 2);
  u16* h   = (u16*)alloc((size_t)ROWS_T * HDIM * 2);
  u16* y   = (u16*)alloc((size_t)ROWS_T * DDIM * 2);
  int*   token_ids = (int*)alloc(ROWS_T * 4);
  int*   tok_idx   = (int*)alloc(N_TOK * 2 * 4);
  int*   pos       = (int*)alloc(N_TOK * 2 * 4);
  float* wts       = (float*)alloc(N_TOK * 2 * 4);
  int*   counts  = (int*)alloc(8 * 4);
  int*   offsets = (int*)alloc(9 * 4);
  int*   cursors = (int*)alloc(8 * 4);
  int*   ntiles  = (int*)alloc(4);
  int4*  tiles   = (int4*)alloc(MAXTILES * 16);

  hipMemsetAsync(counts, 0, 8 * 4, stream);
  k_gate<<<N_TOK / 4, 256, 0, stream>>>(x, gw, bias, tok_idx, wts, counts, xb);
  k_scan<<<1, 64, 0, stream>>>(counts, offsets, cursors, ntiles, tiles);
  k_build<<<(N_TOK + 255) / 256, 256, 0, stream>>>(tok_idx, offsets, cursors, token_ids, pos);

  k_gemm1<<<(HDIM / 128) * MAXTILES, 256, 0, stream>>>(xb, Wg, Wsg, Wu, Wsu,
                                                       token_ids, ntiles, tiles, h);
  k_gemm2<<<(DDIM / 128) * MAXTILES, 256, 0, stream>>>(h, Wd, Wsd, ntiles, tiles, y);
  k_comb<<<N_TOK, 256, 0, stream>>>(y, pos, wts, out);
}

// Round 10
// 873.799 us; speedup vs baseline: 1.2319x; 1.2319x over previous
//
#include <hip/hip_runtime.h>
#include <hip/hip_bf16.h>

#define N_TOK 8192
#define DDIM  2048
#define HDIM  1408
#define ROWS_R 16384
#define ROWS_T 24576
#define MAXTILES 104
#define BM 256
#define BN 128
#define BK 64

typedef unsigned short u16;
typedef unsigned int   u32;
typedef __bf16 bf16x8 __attribute__((ext_vector_type(8)));
typedef float  f32x4  __attribute__((ext_vector_type(4)));

__device__ __forceinline__ u16 f2bf(float f) {
  union { float f; u32 u; } v; v.f = f;
  u32 u = v.u;
  return (u16)((u + 0x7fffu + ((u >> 16) & 1u)) >> 16);
}
__device__ __forceinline__ float bf2f(u16 b) {
  union { u32 u; float f; } v; v.u = ((u32)b) << 16; return v.f;
}

typedef __attribute__((address_space(1))) void gvoid;
typedef __attribute__((address_space(3))) void lvoid;
__device__ __forceinline__ void gload16(const void* g, void* l) {
  __builtin_amdgcn_global_load_lds((gvoid*)g, (lvoid*)l, 16, 0, 0);
}

#define BAR __builtin_amdgcn_s_barrier()
#define SP1 __builtin_amdgcn_s_setprio(1)
#define SP0 __builtin_amdgcn_s_setprio(0)
#define LGK0 do { asm volatile("s_waitcnt lgkmcnt(0)" ::: "memory"); \
                  __builtin_amdgcn_sched_barrier(0); } while (0)
#define VMCNT(n) asm volatile("s_waitcnt vmcnt(" #n ")" ::: "memory")

// read A fragments: 2 m-frags x 2 kk  (4 x ds_read_b128)
#define READ_AF(base, mb, dst) { \
  _Pragma("unroll") for (int m_ = 0; m_ < 2; ++m_) { \
    int r_ = wr * 64 + ((mb) + m_) * 16 + l15; \
    _Pragma("unroll") for (int kk_ = 0; kk_ < 2; ++kk_) { \
      int cch_ = kk_ * 4 + lhi; \
      (dst)[m_ * 2 + kk_] = *(const bf16x8*)((const char*)(base) + r_ * 128 + ((cch_ ^ (r_ & 7)) * 16)); } } }

// read B fragments: 4 n-frags x 2 kk  (8 x ds_read_b128)
#define READ_BF(base, dst) { \
  _Pragma("unroll") for (int n_ = 0; n_ < 4; ++n_) { \
    int r_ = wc * 64 + n_ * 16 + l15; \
    _Pragma("unroll") for (int kk_ = 0; kk_ < 2; ++kk_) { \
      int cch_ = kk_ * 4 + lhi; \
      (dst)[n_ * 2 + kk_] = *(const bf16x8*)((const char*)(base) + r_ * 128 + ((cch_ ^ (r_ & 7)) * 16)); } } }

// one C-quadrant: 2m x 4n x 2kk = 16 MFMA
#define MFMAQ(AF, BB, ACC, MB) { \
  _Pragma("unroll") for (int m_ = 0; m_ < 2; ++m_) \
  _Pragma("unroll") for (int n_ = 0; n_ < 4; ++n_) \
  _Pragma("unroll") for (int kk_ = 0; kk_ < 2; ++kk_) \
    (ACC)[(MB) + m_][n_] = __builtin_amdgcn_mfma_f32_16x16x32_bf16((AF)[m_ * 2 + kk_], (BB)[n_ * 2 + kk_], (ACC)[(MB) + m_][n_], 0, 0, 0); }

// ---------------- gating (+ fused x -> bf16 conversion) ----------------
__global__ void k_gate(const float* __restrict__ x, const float* __restrict__ gw,
                       const float* __restrict__ bias, int* __restrict__ tok_idx,
                       float* __restrict__ wts, int* __restrict__ counts,
                       u16* __restrict__ xb) {
  int lane = threadIdx.x & 63;
  int n = blockIdx.x * 4 + (threadIdx.x >> 6);
  const float* xr = x + (size_t)n * DDIM;
  u16* xbr = xb + (size_t)n * DDIM;
  float acc[8];
#pragma unroll
  for (int e = 0; e < 8; ++e) acc[e] = 0.f;
#pragma unroll 2
  for (int j0 = 0; j0 < DDIM; j0 += 256) {
    float4 xv = *(const float4*)(xr + j0 + lane * 4);
    u32 p0 = (u32)f2bf(xv.x) | ((u32)f2bf(xv.y) << 16);
    u32 p1 = (u32)f2bf(xv.z) | ((u32)f2bf(xv.w) << 16);
    *(uint2*)(xbr + j0 + lane * 4) = make_uint2(p0, p1);
#pragma unroll
    for (int e = 0; e < 8; ++e) {
      float4 gv = *(const float4*)(gw + e * DDIM + j0 + lane * 4);
      acc[e] += xv.x * gv.x + xv.y * gv.y + xv.z * gv.z + xv.w * gv.w;
    }
  }
#pragma unroll
  for (int e = 0; e < 8; ++e) {
#pragma unroll
    for (int off = 32; off > 0; off >>= 1) acc[e] += __shfl_xor(acc[e], off);
  }
  if (lane == 0) {
    float m = acc[0];
    for (int e = 1; e < 8; ++e) m = fmaxf(m, acc[e]);
    float p[8];
    for (int e = 0; e < 8; ++e) p[e] = expf(acc[e] - m);
    float b0[8];
    for (int e = 0; e < 8; ++e) b0[e] = acc[e] + bias[e];
    int i0 = 0;
    for (int e = 1; e < 8; ++e) if (b0[e] > b0[i0]) i0 = e;
    int i1 = (i0 == 0) ? 1 : 0;
    for (int e = 0; e < 8; ++e) if (e != i0 && b0[e] > b0[i1]) i1 = e;
    float w0 = p[i0], w1 = p[i1], inv = 1.f / (w0 + w1);
    tok_idx[2 * n] = i0; tok_idx[2 * n + 1] = i1;
    wts[2 * n] = w0 * inv; wts[2 * n + 1] = w1 * inv;
    atomicAdd(&counts[i0], 1); atomicAdd(&counts[i1], 1);
  }
}

// ---------------- scan + tile table (BM=256 tiles) ----------------
__global__ void k_scan(const int* __restrict__ counts, int* __restrict__ offsets,
                       int* __restrict__ cursors, int* __restrict__ ntiles,
                       int4* __restrict__ tiles) {
  if (threadIdx.x != 0 || blockIdx.x != 0) return;
  int off = 0, idx = 0;
  for (int e = 0; e < 8; ++e) {
    offsets[e] = off; cursors[e] = 0;
    int T = counts[e];
    for (int r = 0; r < T; r += BM) {
      int nr = T - r; if (nr > BM) nr = BM;
      tiles[idx++] = make_int4(e, off + r, nr, 0);
    }
    off += T;
  }
  offsets[8] = off;
  for (int r = 0; r < N_TOK; r += BM)
    tiles[idx++] = make_int4(8, ROWS_R + r, BM, 0);
  *ntiles = idx;
}

// ---------------- build token lists ----------------
__global__ void k_build(const int* __restrict__ tok_idx, const int* __restrict__ offsets,
                        int* __restrict__ cursors, int* __restrict__ token_ids,
                        int* __restrict__ pos) {
  int n = blockIdx.x * blockDim.x + threadIdx.x;
  if (n >= N_TOK) return;
#pragma unroll
  for (int s = 0; s < 2; ++s) {
    int e = tok_idx[2 * n + s];
    int p = offsets[e] + atomicAdd(&cursors[e], 1);
    token_ids[p] = n;
    pos[2 * n + s] = p;
  }
  token_ids[ROWS_R + n] = n;
}

// ---------------- fused f32 -> bf16 convert for all 9 weight tensors ----------------
__global__ void k_convall(const float* __restrict__ Wg, const float* __restrict__ Wsg,
                          const float* __restrict__ Wu, const float* __restrict__ Wsu,
                          const float* __restrict__ Wd, const float* __restrict__ Wsd,
                          u16* __restrict__ wgb, u16* __restrict__ wub, u16* __restrict__ wdb) {
  const long PER = (long)9 * HDIM * DDIM / 8;
  const long BIG = (long)8 * HDIM * DDIM / 8;
  const long TOT = 3 * PER;
  long stride = (long)gridDim.x * blockDim.x;
  for (long i = (long)blockIdx.x * blockDim.x + threadIdx.x; i < TOT; i += stride) {
    int g = (int)(i / PER);
    long r = i - (long)g * PER;
    const float* src; u16* dst;
    if (g == 0)      { dst = wgb; src = (r < BIG) ? Wg + r * 8 : Wsg + (r - BIG) * 8; }
    else if (g == 1) { dst = wub; src = (r < BIG) ? Wu + r * 8 : Wsu + (r - BIG) * 8; }
    else             { dst = wdb; src = (r < BIG) ? Wd + r * 8 : Wsd + (r - BIG) * 8; }
    float4 a = ((const float4*)src)[0], b = ((const float4*)src)[1];
    u32 p0 = (u32)f2bf(a.x) | ((u32)f2bf(a.y) << 16);
    u32 p1 = (u32)f2bf(a.z) | ((u32)f2bf(a.w) << 16);
    u32 p2 = (u32)f2bf(b.x) | ((u32)f2bf(b.y) << 16);
    u32 p3 = (u32)f2bf(b.z) | ((u32)f2bf(b.w) << 16);
    ((uint4*)dst)[r] = make_uint4(p0, p1, p2, p3);
  }
}

// ---------------- GEMM1: h = silu(x Wg^T) * (x Wu^T), R2 4-phase (measured 348us) ----------------
__global__ __launch_bounds__(512, 2) void k_gemm1(
    const u16* __restrict__ xb, const u16* __restrict__ wgb,
    const int* __restrict__ token_ids, const int* __restrict__ ntiles,
    const int4* __restrict__ tiles, u16* __restrict__ h) {
  __shared__ u16 As[2][BM * BK];    // 64 KB
  __shared__ u16 Bgs[2][BN * BK];   // 32 KB
  __shared__ u16 Bus[2][BN * BK];   // 32 KB

  int ntl = *ntiles;
  int nwg = (HDIM / BN) * ntl;
  int bid = blockIdx.x;
  if (bid >= nwg) return;
  int q8 = nwg >> 3, r8 = nwg & 7;
  int xcd = bid & 7, pp = bid >> 3;
  int lid = (xcd < r8 ? xcd * (q8 + 1) : r8 * (q8 + 1) + (xcd - r8) * q8) + pp;
  int bx = lid / ntl, tile = lid - bx * ntl;

  int4 tl = tiles[tile];
  int set = tl.x, grow = tl.y, nrows = tl.z;

  int t = threadIdx.x;
  int wid = t >> 6, lane = t & 63;
  int wr = wid >> 1, wc = wid & 1;
  int l15 = lane & 15, lhi = lane >> 4;

  const u16* aptr[4];
#pragma unroll
  for (int i = 0; i < 4; ++i) {
    int chunk = i * 512 + t;
    int r = chunk >> 3, cc = chunk & 7;
    int c = cc ^ (r & 7);
    int rr = r < nrows ? r : nrows - 1;
    int tok = token_ids[grow + rr];
    aptr[i] = xb + (size_t)tok * DDIM + c * 8;
  }
  const u16* gptr[2];
#pragma unroll
  for (int i = 0; i < 2; ++i) {
    int chunk = i * 512 + t;
    int r = chunk >> 3, cc = chunk & 7;
    int c = cc ^ (r & 7);
    gptr[i] = wgb + (size_t)set * (HDIM * DDIM) + (size_t)(bx * BN + r) * DDIM + c * 8;
  }
  const size_t WUOFF = (size_t)9 * HDIM * DDIM;  // wub sits right after wgb

#define G1_A0(b, k0) { gload16(aptr[0] + (k0), (char*)As[b] + (size_t)t * 16); \
                       gload16(aptr[1] + (k0), (char*)As[b] + (size_t)(512 + t) * 16); }
#define G1_A1(b, k0) { gload16(aptr[2] + (k0), (char*)As[b] + (size_t)(1024 + t) * 16); \
                       gload16(aptr[3] + (k0), (char*)As[b] + (size_t)(1536 + t) * 16); }
#define G1_BG(b, k0) { gload16(gptr[0] + (k0), (char*)Bgs[b] + (size_t)t * 16); \
                       gload16(gptr[1] + (k0), (char*)Bgs[b] + (size_t)(512 + t) * 16); }
#define G1_BU(b, k0) { gload16(gptr[0] + WUOFF + (k0), (char*)Bus[b] + (size_t)t * 16); \
                       gload16(gptr[1] + WUOFF + (k0), (char*)Bus[b] + (size_t)(512 + t) * 16); }

  f32x4 accg[4][4], accu[4][4];
  f32x4 z = {0.f, 0.f, 0.f, 0.f};
#pragma unroll
  for (int m = 0; m < 4; ++m)
#pragma unroll
    for (int n = 0; n < 4; ++n) { accg[m][n] = z; accu[m][n] = z; }

  const int NK = DDIM / BK;  // 32

  VMCNT(0);  // baseline the counter (pre-loop scalar gather loads drained)
  G1_A0(0, 0); G1_A1(0, 0); G1_BG(0, 0); G1_BU(0, 0);
  VMCNT(2); BAR;  // A0,A1,Bg of tile0 resident; Bu may be in flight

  for (int kt = 0; kt < NK - 1; ++kt) {
    int cur = kt & 1, nxt = cur ^ 1;
    int k1 = (kt + 1) * BK;
    bf16x8 a01[4], a23[4], bb[8];
    // ph0: m01 x g
    READ_AF(As[cur], 0, a01);
    READ_BF(Bgs[cur], bb);
    G1_A0(nxt, k1);
    BAR; LGK0;
    SP1; MFMAQ(a01, bb, accg, 0); SP0;
    BAR;
    // ph1: m23 x g
    READ_AF(As[cur], 2, a23);
    G1_A1(nxt, k1);
    BAR; LGK0;
    SP1; MFMAQ(a23, bb, accg, 2); SP0;
    VMCNT(4); BAR;  // Bu(t) now resident (leaves A0,A1(t+1) in flight)
    // ph2: m01 x u
    READ_BF(Bus[cur], bb);
    G1_BG(nxt, k1);
    BAR; LGK0;
    SP1; MFMAQ(a01, bb, accu, 0); SP0;
    BAR;
    // ph3: m23 x u
    G1_BU(nxt, k1);
    BAR;
    SP1; MFMAQ(a23, bb, accu, 2); SP0;
    VMCNT(2); BAR;  // A0,A1,Bg(t+1) resident (leaves Bu(t+1) in flight)
  }
  {  // epilogue: tile NK-1, fully resident
    int cur = (NK - 1) & 1;
    VMCNT(0); BAR;
    bf16x8 a01[4], a23[4], bg8[8], bu8[8];
    READ_AF(As[cur], 0, a01);
    READ_AF(As[cur], 2, a23);
    READ_BF(Bgs[cur], bg8);
    READ_BF(Bus[cur], bu8);
    LGK0;
    MFMAQ(a01, bg8, accg, 0); MFMAQ(a23, bg8, accg, 2);
    MFMAQ(a01, bu8, accu, 0); MFMAQ(a23, bu8, accu, 2);
  }

#pragma unroll
  for (int m = 0; m < 4; ++m) {
#pragma unroll
    for (int n = 0; n < 4; ++n) {
      int col = bx * BN + wc * 64 + n * 16 + l15;
#pragma unroll
      for (int qq = 0; qq < 4; ++qq) {
        int rl = wr * 64 + m * 16 + lhi * 4 + qq;
        if (rl < nrows) {
          float g = accg[m][n][qq], u = accu[m][n][qq];
          float hv = g / (1.f + expf(-g)) * u;
          h[(size_t)(grow + rl) * HDIM + col] = f2bf(hv);
        }
      }
    }
  }
#undef G1_A0
#undef G1_A1
#undef G1_BG
#undef G1_BU
}

// ---------------- GEMM2: y = h Wd^T — exact clone of gemm1's schedule ----------------
// B panel = 256 Wd rows split as two 128-row halves (B0s/B1s play Bgs/Bus roles).
__global__ __launch_bounds__(512, 2) void k_gemm2(
    const u16* __restrict__ h, const u16* __restrict__ wdb,
    const int* __restrict__ ntiles, const int4* __restrict__ tiles,
    u16* __restrict__ y) {
  __shared__ u16 As[2][BM * BK];    // 64 KB
  __shared__ u16 B0s[2][BN * BK];   // 32 KB
  __shared__ u16 B1s[2][BN * BK];   // 32 KB

  int ntl = *ntiles;
  int nwg = (DDIM / 256) * ntl;
  int bid = blockIdx.x;
  if (bid >= nwg) return;
  int q8 = nwg >> 3, r8 = nwg & 7;
  int xcd = bid & 7, pp = bid >> 3;
  int lid = (xcd < r8 ? xcd * (q8 + 1) : r8 * (q8 + 1) + (xcd - r8) * q8) + pp;
  int bx = lid / ntl, tile = lid - bx * ntl;

  int4 tl = tiles[tile];
  int set = tl.x, grow = tl.y, nrows = tl.z;

  int t = threadIdx.x;
  int wid = t >> 6, lane = t & 63;
  int wr = wid >> 1, wc = wid & 1;
  int l15 = lane & 15, lhi = lane >> 4;

  const u16* aptr[4];
#pragma unroll
  for (int i = 0; i < 4; ++i) {
    int chunk = i * 512 + t;
    int r = chunk >> 3, cc = chunk & 7;
    int c = cc ^ (r & 7);
    aptr[i] = h + (size_t)(grow + r) * HDIM + c * 8;   // h rows valid through ROWS_T
  }
  const u16* bptr[4];
#pragma unroll
  for (int i = 0; i < 4; ++i) {
    int chunk = i * 512 + t;
    int r = chunk >> 3, cc = chunk & 7;   // r in [0,256)
    int c = cc ^ (r & 7);
    bptr[i] = wdb + (size_t)set * (DDIM * HDIM) + (size_t)(bx * 256 + r) * HDIM + c * 8;
  }

#define G2_A0(b, k0) { gload16(aptr[0] + (k0), (char*)As[b] + (size_t)t * 16); \
                       gload16(aptr[1] + (k0), (char*)As[b] + (size_t)(512 + t) * 16); }
#define G2_A1(b, k0) { gload16(aptr[2] + (k0), (char*)As[b] + (size_t)(1024 + t) * 16); \
                       gload16(aptr[3] + (k0), (char*)As[b] + (size_t)(1536 + t) * 16); }
#define G2_B0(b, k0) { gload16(bptr[0] + (k0), (char*)B0s[b] + (size_t)t * 16); \
                       gload16(bptr[1] + (k0), (char*)B0s[b] + (size_t)(512 + t) * 16); }
#define G2_B1(b, k0) { gload16(bptr[2] + (k0), (char*)B1s[b] + (size_t)t * 16); \
                       gload16(bptr[3] + (k0), (char*)B1s[b] + (size_t)(512 + t) * 16); }

  f32x4 acc0[4][4], acc1[4][4];
  f32x4 z = {0.f, 0.f, 0.f, 0.f};
#pragma unroll
  for (int m = 0; m < 4; ++m)
#pragma unroll
    for (int n = 0; n < 4; ++n) { acc0[m][n] = z; acc1[m][n] = z; }

  const int NK = HDIM / BK;  // 22

  VMCNT(0);
  G2_A0(0, 0); G2_A1(0, 0); G2_B0(0, 0); G2_B1(0, 0);
  VMCNT(2); BAR;

  for (int kt = 0; kt < NK - 1; ++kt) {
    int cur = kt & 1, nxt = cur ^ 1;
    int k1 = (kt + 1) * BK;
    bf16x8 a01[4], a23[4], bb[8];
    // ph0: m01 x panel0
    READ_AF(As[cur], 0, a01);
    READ_BF(B0s[cur], bb);
    G2_A0(nxt, k1);
    BAR; LGK0;
    SP1; MFMAQ(a01, bb, acc0, 0); SP0;
    BAR;
    // ph1: m23 x panel0
    READ_AF(As[cur], 2, a23);
    G2_A1(nxt, k1);
    BAR; LGK0;
    SP1; MFMAQ(a23, bb, acc0, 2); SP0;
    VMCNT(4); BAR;
    // ph2: m01 x panel1
    READ_BF(B1s[cur], bb);
    G2_B0(nxt, k1);
    BAR; LGK0;
    SP1; MFMAQ(a01, bb, acc1, 0); SP0;
    BAR;
    // ph3: m23 x panel1
    G2_B1(nxt, k1);
    BAR;
    SP1; MFMAQ(a23, bb, acc1, 2); SP0;
    VMCNT(2); BAR;
  }
  {
    int cur = (NK - 1) & 1;
    VMCNT(0); BAR;
    bf16x8 a01[4], a23[4], b08[8], b18[8];
    READ_AF(As[cur], 0, a01);
    READ_AF(As[cur], 2, a23);
    READ_BF(B0s[cur], b08);
    READ_BF(B1s[cur], b18);
    LGK0;
    MFMAQ(a01, b08, acc0, 0); MFMAQ(a23, b08, acc0, 2);
    MFMAQ(a01, b18, acc1, 0); MFMAQ(a23, b18, acc1, 2);
  }

#pragma unroll
  for (int m = 0; m < 4; ++m) {
#pragma unroll
    for (int n = 0; n < 4; ++n) {
      int col = bx * 256 + wc * 64 + n * 16 + l15;
#pragma unroll
      for (int qq = 0; qq < 4; ++qq) {
        int rl = wr * 64 + m * 16 + lhi * 4 + qq;
        if (rl < nrows) {
          size_t rowoff = (size_t)(grow + rl) * DDIM;
          y[rowoff + col]       = f2bf(acc0[m][n][qq]);
          y[rowoff + col + 128] = f2bf(acc1[m][n][qq]);
        }
      }
    }
  }
#undef G2_A0
#undef G2_A1
#undef G2_B0
#undef G2_B1
}

// ---------------- combine ----------------
__global__ void k_comb(const u16* __restrict__ y, const int* __restrict__ pos,
                       const float* __restrict__ wts, float* __restrict__ out) {
  int n = blockIdx.x;
  int c8 = threadIdx.x;
  int p0 = pos[2 * n], p1 = pos[2 * n + 1];
  float w0 = wts[2 * n], w1 = wts[2 * n + 1];
  uint4 a = ((const uint4*)(y + (size_t)p0 * DDIM))[c8];
  uint4 b = ((const uint4*)(y + (size_t)p1 * DDIM))[c8];
  uint4 c = ((const uint4*)(y + (size_t)(ROWS_R + n) * DDIM))[c8];
  float* o = out + (size_t)n * DDIM + c8 * 8;
#pragma unroll
  for (int j = 0; j < 4; ++j) {
    u32 ua = ((const u32*)&a)[j], ub = ((const u32*)&b)[j], uc = ((const u32*)&c)[j];
    o[2 * j]     = w0 * bf2f((u16)(ua & 0xffff)) + w1 * bf2f((u16)(ub & 0xffff)) + bf2f((u16)(uc & 0xffff));
    o[2 * j + 1] = w0 * bf2f((u16)(ua >> 16))    + w1 * bf2f((u16)(ub >> 16))    + bf2f((u16)(uc >> 16));
  }
}

extern "C" void kernel_launch(void* const* d_in, const int* in_sizes, int n_in,
                              void* d_out, int out_size, void* d_ws, size_t ws_size,
                              hipStream_t stream) {
  const float* x    = (const float*)d_in[0];
  const float* gw   = (const float*)d_in[1];
  const float* bias = (const float*)d_in[2];
  const float* Wg   = (const float*)d_in[3];
  const float* Wu   = (const float*)d_in[4];
  const float* Wd   = (const float*)d_in[5];
  const float* Wsg  = (const float*)d_in[6];
  const float* Wsu  = (const float*)d_in[7];
  const float* Wsd  = (const float*)d_in[8];
  float* out = (float*)d_out;

  char* ws = (char*)d_ws;
  size_t off = 0;
  auto alloc = [&](size_t bytes) -> void* {
    void* p = ws + off;
    off += (bytes + 255) & ~(size_t)255;
    return p;
  };
  u16* xb  = (u16*)alloc((size_t)N_TOK * DDIM * 2);
  u16* wgb = (u16*)alloc((size_t)9 * HDIM * DDIM * 2);  // wub must follow wgb (WUOFF)
  u16* wub = (u16*)alloc((size_t)9 * HDIM * DDIM * 2);
  u16* wdb = (u16*)alloc((size_t)9 * DDIM * HDIM * 2);
  u16* h   = (u16*)alloc((size_t)ROWS_T * HDIM * 2);
  u16* y   = (u16*)alloc((size_t)ROWS_T * DDIM * 2);
  int*   token_ids = (int*)alloc(ROWS_T * 4);
  int*   tok_idx   = (int*)alloc(N_TOK * 2 * 4);
  int*   pos       = (int*)alloc(N_TOK * 2 * 4);
  float* wts       = (float*)alloc(N_TOK * 2 * 4);
  int*   counts  = (int*)alloc(8 * 4);
  int*   offsets = (int*)alloc(9 * 4);
  int*   cursors = (int*)alloc(8 * 4);
  int*   ntiles  = (int*)alloc(4);
  int4*  tiles   = (int4*)alloc(MAXTILES * 16);

  hipMemsetAsync(counts, 0, 8 * 4, stream);
  k_gate<<<N_TOK / 4, 256, 0, stream>>>(x, gw, bias, tok_idx, wts, counts, xb);
  k_scan<<<1, 64, 0, stream>>>(counts, offsets, cursors, ntiles, tiles);
  k_build<<<(N_TOK + 255) / 256, 256, 0, stream>>>(tok_idx, offsets, cursors, token_ids, pos);

  k_convall<<<4096, 256, 0, stream>>>(Wg, Wsg, Wu, Wsu, Wd, Wsd, wgb, wub, wdb);

  k_gemm1<<<(HDIM / BN) * MAXTILES, 512, 0, stream>>>(xb, wgb, token_ids, ntiles, tiles, h);
  k_gemm2<<<(DDIM / 256) * MAXTILES, 512, 0, stream>>>(h, wdb, ntiles, tiles, y);
  k_comb<<<N_TOK, 256, 0, stream>>>(y, pos, wts, out);
}